// Round 1
// baseline (472.058 us; speedup 1.0000x reference)
//
#include <hip/hip_runtime.h>
#include <math.h>

#define NN 4096
#define DD 128
#define RB 4            // rows per block
#define ALPHA_C 16.0f
#define KSEL 32         // threshold = (K+1)-th smallest, 0-based index K

// ---- float <-> order-preserving u32 key ----
__device__ __forceinline__ unsigned f2k(float f) {
  unsigned b = __float_as_uint(f);
  return (b & 0x80000000u) ? ~b : (b | 0x80000000u);
}
__device__ __forceinline__ float k2f(unsigned k) {
  unsigned b = (k & 0x80000000u) ? (k & 0x7FFFFFFFu) : ~k;
  return __uint_as_float(b);
}

// ---- block reductions (256 threads = 4 waves), deterministic fixed tree ----
__device__ __forceinline__ double bsum_d(double v, double* red, int tid) {
  #pragma unroll
  for (int o = 32; o > 0; o >>= 1) v += __shfl_down(v, o, 64);
  __syncthreads();
  if ((tid & 63) == 0) red[tid >> 6] = v;
  __syncthreads();
  double r = red[0] + red[1] + red[2] + red[3];
  __syncthreads();
  return r;
}
__device__ __forceinline__ int bsum_i(int v, int* red, int tid) {
  #pragma unroll
  for (int o = 32; o > 0; o >>= 1) v += __shfl_down(v, o, 64);
  __syncthreads();
  if ((tid & 63) == 0) red[tid >> 6] = v;
  __syncthreads();
  int r = red[0] + red[1] + red[2] + red[3];
  __syncthreads();
  return r;
}
__device__ __forceinline__ float bmin_f(float v, float* red, int tid) {
  #pragma unroll
  for (int o = 32; o > 0; o >>= 1) v = fminf(v, __shfl_down(v, o, 64));
  __syncthreads();
  if ((tid & 63) == 0) red[tid >> 6] = v;
  __syncthreads();
  float r = fminf(fminf(red[0], red[1]), fminf(red[2], red[3]));
  __syncthreads();
  return r;
}

// ---- kernel 1: transpose x[N][D] -> xT[D][N] for coalesced j-reads ----
__global__ void nca_transpose(const float* __restrict__ x, float* __restrict__ xT) {
  int idx = blockIdx.x * blockDim.x + threadIdx.x;
  int stride = gridDim.x * blockDim.x;
  for (int i = idx; i < NN * DD; i += stride) {
    int n = i >> 7;        // / DD
    int d = i & (DD - 1);  // % DD
    xT[d * NN + n] = x[i];
  }
}

// ---- kernel 2: per-row everything; 4 rows per block, sims in registers ----
__global__ __launch_bounds__(256) void nca_rows(
    const float* __restrict__ x, const float* __restrict__ xT,
    const int* __restrict__ tgt, float* __restrict__ row_loss,
    float* __restrict__ out) {
  __shared__ float xi[RB][DD];
  __shared__ double redd[4];
  __shared__ int   redi[4];
  __shared__ float redf[4];

  const int tid = threadIdx.x;
  const int i0  = blockIdx.x * RB;

  for (int k = tid; k < RB * DD; k += 256)
    xi[k >> 7][k & (DD - 1)] = x[i0 * DD + k];
  __syncthreads();

  // f64 self-dots (decision sim[i][i] < 1.0 must match f64 reference)
  double selfd[RB];
  #pragma unroll
  for (int r = 0; r < RB; ++r) {
    double s = 0.0;
    if (tid < DD) { double v = (double)xi[r][tid]; s = v * v; }
    selfd[r] = bsum_d(s, redd, tid);
  }

  // sims: thread owns j = k*1024 + tid*4 + q  (k,q in 0..3 -> 16 per thread)
  float acc[RB][16];
  #pragma unroll
  for (int r = 0; r < RB; ++r)
    #pragma unroll
    for (int c = 0; c < 16; ++c) acc[r][c] = 0.0f;

  const int jb = tid << 2;
  for (int d = 0; d < DD; ++d) {
    float a0 = xi[0][d], a1 = xi[1][d], a2 = xi[2][d], a3 = xi[3][d];
    #pragma unroll
    for (int k = 0; k < 4; ++k) {
      float4 v = *reinterpret_cast<const float4*>(xT + d * NN + (k << 10) + jb);
      float vv[4] = {v.x, v.y, v.z, v.w};
      #pragma unroll
      for (int q = 0; q < 4; ++q) {
        acc[0][k * 4 + q] = fmaf(a0, vv[q], acc[0][k * 4 + q]);
        acc[1][k * 4 + q] = fmaf(a1, vv[q], acc[1][k * 4 + q]);
        acc[2][k * 4 + q] = fmaf(a2, vv[q], acc[2][k * 4 + q]);
        acc[3][k * 4 + q] = fmaf(a3, vv[q], acc[3][k * 4 + q]);
      }
    }
  }

  int tj[16];
  #pragma unroll
  for (int k = 0; k < 4; ++k) {
    int4 t4 = *reinterpret_cast<const int4*>(tgt + (k << 10) + jb);
    tj[k * 4 + 0] = t4.x; tj[k * 4 + 1] = t4.y;
    tj[k * 4 + 2] = t4.z; tj[k * 4 + 3] = t4.w;
  }

  for (int r = 0; r < RB; ++r) {
    const int i = i0 + r;
    const int ti = tgt[i];
    const bool self_pos = (selfd[r] < 1.0);  // f64 decision

    // base = mean of full row (includes self)
    double bs = 0.0;
    #pragma unroll
    for (int c = 0; c < 16; ++c) bs += (double)acc[r][c];
    const float basef = (float)(bsum_d(bs, redd, tid) * (1.0 / NN));

    // keys: excluded entries (self with sim>=1) -> max key
    unsigned key[16];
    #pragma unroll
    for (int c = 0; c < 16; ++c) {
      int j = ((c >> 2) << 10) + jb + (c & 3);
      bool excl = (j == i) && (!self_pos);
      key[c] = excl ? 0xFFFFFFFFu : f2k(acc[r][c]);
    }

    // radix-select exact rank-KSEL key (33rd smallest)
    unsigned pref = 0; int want = KSEL;
    for (int b = 31; b >= 0; --b) {
      unsigned test = pref << 1;
      int cnt = 0;
      #pragma unroll
      for (int c = 0; c < 16; ++c) cnt += ((key[c] >> b) == test) ? 1 : 0;
      int tot = bsum_i(cnt, redi, tid);
      if (want < tot) pref = test;
      else { want -= tot; pref = test | 1u; }
    }
    const float thr = k2f(pref);

    // pass 2: weighted sums, min-pos, diagnostics
    double psum = 0.0, nsum = 0.0, pss = 0.0, nss = 0.0;
    float minp = __builtin_inff();
    int hasp = 0, pct = 0, nct = 0;
    #pragma unroll
    for (int c = 0; c < 16; ++c) {
      int j = ((c >> 2) << 10) + jb + (c & 3);
      float s = acc[r][c];
      bool same = (tj[c] == ti);
      bool vpos = same && ((j == i) ? self_pos : (s < 1.0f));
      bool vneg = !same;
      if (vpos) { minp = fminf(minp, s); pss += (double)s; pct++; }
      if (vneg) { nss += (double)s; nct++; }
      if (s < thr) {
        float w = expf(ALPHA_C * (basef - s));
        if (vpos) { psum += (double)w; hasp = 1; }
        else if (vneg) nsum += (double)w;
      }
    }
    double tpsum = bsum_d(psum, redd, tid);
    double tnsum = bsum_d(nsum, redd, tid);
    float  tminp = bmin_f(minp, redf, tid);
    int    thasp = bsum_i(hasp, redi, tid);

    if (i == NN - 1) {  // block-uniform: diagnostics from last row
      double tps = bsum_d(pss, redd, tid);
      double tns = bsum_d(nss, redd, tid);
      int tpc = bsum_i(pct, redi, tid);
      int tnc = bsum_i(nct, redi, tid);
      if (tid == 0) {
        out[2] = (float)(tps / (double)tpc);
        out[3] = (float)(tns / (double)tnc);
      }
    }

    if (tid == 0) {
      float pl = (thasp > 0) ? (float)tpsum
                             : expf(ALPHA_C * (basef - tminp));
      row_loss[i] = -logf(pl / (pl + (float)tnsum));
    }
  }
}

// ---- kernel 3: deterministic mean of per-row losses ----
__global__ void nca_final(const float* __restrict__ row_loss, float* __restrict__ out) {
  __shared__ double redd[4];
  int tid = threadIdx.x;
  double s = 0.0;
  for (int i = tid; i < NN; i += 256) s += (double)row_loss[i];
  double tot = bsum_d(s, redd, tid);
  if (tid == 0) {
    out[0] = (float)(tot * (1.0 / NN));
    out[1] = 0.0f;  // prec stays 0 in torch code
  }
}

extern "C" void kernel_launch(void* const* d_in, const int* in_sizes, int n_in,
                              void* d_out, int out_size, void* d_ws, size_t ws_size,
                              hipStream_t stream) {
  const float* x  = (const float*)d_in[0];
  const int* tgt  = (const int*)d_in[1];
  float* out      = (float*)d_out;
  // ws: xT (N*D f32 = 2 MB) then row_loss (N f32 = 16 KB)
  float* xT       = (float*)d_ws;
  float* row_loss = xT + (size_t)NN * DD;

  nca_transpose<<<512, 256, 0, stream>>>(x, xT);
  nca_rows<<<NN / RB, 256, 0, stream>>>(x, xT, tgt, row_loss, out);
  nca_final<<<1, 256, 0, stream>>>(row_loss, out);
}

// Round 2
// 183.775 us; speedup vs baseline: 2.5687x; 2.5687x over previous
//
#include <hip/hip_runtime.h>
#include <math.h>

#define NN 4096
#define DD 128
#define RB 4            // rows per block == waves per block
#define ALPHA_C 16.0f
#define KSEL 32         // threshold = (K+1)-th smallest, 0-based index K

// ---- float <-> order-preserving u32 key ----
__device__ __forceinline__ unsigned f2k(float f) {
  unsigned b = __float_as_uint(f);
  return (b & 0x80000000u) ? ~b : (b | 0x80000000u);
}
__device__ __forceinline__ float k2f(unsigned k) {
  unsigned b = (k & 0x80000000u) ? (k & 0x7FFFFFFFu) : ~k;
  return __uint_as_float(b);
}

// ---- wave (64-lane) butterfly reductions: no barriers, all lanes get result ----
__device__ __forceinline__ double wsum_d(double v) {
  #pragma unroll
  for (int m = 32; m; m >>= 1) v += __shfl_xor(v, m, 64);
  return v;
}
__device__ __forceinline__ int wsum_i(int v) {
  #pragma unroll
  for (int m = 32; m; m >>= 1) v += __shfl_xor(v, m, 64);
  return v;
}
__device__ __forceinline__ float wmin_f(float v) {
  #pragma unroll
  for (int m = 32; m; m >>= 1) v = fminf(v, __shfl_xor(v, m, 64));
  return v;
}

// ---- kernel 1: transpose x[N][D] -> xT[D][N] for coalesced j-reads ----
__global__ void nca_transpose(const float* __restrict__ x, float* __restrict__ xT) {
  int idx = blockIdx.x * blockDim.x + threadIdx.x;
  int stride = gridDim.x * blockDim.x;
  for (int i = idx; i < NN * DD; i += stride) {
    int n = i >> 7;        // / DD
    int d = i & (DD - 1);  // % DD
    xT[d * NN + n] = x[i];
  }
}

// ---- kernel 2: 4 rows per block; sims via block-wide FMA, then 1 wave = 1 row ----
__global__ __launch_bounds__(256) void nca_rows(
    const float* __restrict__ x, const float* __restrict__ xT,
    const int* __restrict__ tgt, float* __restrict__ row_loss,
    float* __restrict__ out) {
  __shared__ float xi[RB][DD];
  __shared__ float sim[RB][NN];   // 64 KB

  const int tid = threadIdx.x;
  const int i0  = blockIdx.x * RB;

  for (int k = tid; k < RB * DD; k += 256)
    xi[k >> 7][k & (DD - 1)] = x[i0 * DD + k];
  __syncthreads();

  // ---- phase 1: sims, thread owns j = k*1024 + tid*4 + q (16 per thread) ----
  float acc[RB][16];
  #pragma unroll
  for (int r = 0; r < RB; ++r)
    #pragma unroll
    for (int c = 0; c < 16; ++c) acc[r][c] = 0.0f;

  const int jb = tid << 2;
  #pragma unroll 2
  for (int d = 0; d < DD; ++d) {
    float a0 = xi[0][d], a1 = xi[1][d], a2 = xi[2][d], a3 = xi[3][d];
    #pragma unroll
    for (int k = 0; k < 4; ++k) {
      float4 v = *reinterpret_cast<const float4*>(xT + d * NN + (k << 10) + jb);
      float vv[4] = {v.x, v.y, v.z, v.w};
      #pragma unroll
      for (int q = 0; q < 4; ++q) {
        acc[0][k * 4 + q] = fmaf(a0, vv[q], acc[0][k * 4 + q]);
        acc[1][k * 4 + q] = fmaf(a1, vv[q], acc[1][k * 4 + q]);
        acc[2][k * 4 + q] = fmaf(a2, vv[q], acc[2][k * 4 + q]);
        acc[3][k * 4 + q] = fmaf(a3, vv[q], acc[3][k * 4 + q]);
      }
    }
  }

  // ---- redistribute: all sims to LDS ----
  #pragma unroll
  for (int r = 0; r < RB; ++r)
    #pragma unroll
    for (int k = 0; k < 4; ++k) {
      float4 v = make_float4(acc[r][k * 4 + 0], acc[r][k * 4 + 1],
                             acc[r][k * 4 + 2], acc[r][k * 4 + 3]);
      *reinterpret_cast<float4*>(&sim[r][(k << 10) + jb]) = v;
    }
  __syncthreads();

  // ---- phase 2: wave w owns row i0+w; lane owns j = kk*256 + lane*4 + q ----
  const int w    = tid >> 6;
  const int lane = tid & 63;
  const int i    = i0 + w;
  const int ti   = tgt[i];
  const int lb   = lane << 2;

  // f64 self-dot (decision sim[i][i] < 1.0 must match f64-accurate reference)
  {
  }
  double sx0 = (double)xi[w][lane], sx1 = (double)xi[w][lane + 64];
  const double selfd = wsum_d(sx0 * sx0 + sx1 * sx1);
  const bool self_pos = (selfd < 1.0);

  // build keys + base (row mean, f64 sum)
  unsigned kv[64];
  double bs = 0.0;
  #pragma unroll
  for (int kk = 0; kk < 16; ++kk) {
    float4 v = *reinterpret_cast<const float4*>(&sim[w][(kk << 8) + lb]);
    float vv[4] = {v.x, v.y, v.z, v.w};
    #pragma unroll
    for (int q = 0; q < 4; ++q) {
      int j = (kk << 8) + lb + q;
      bs += (double)vv[q];
      bool excl = (j == i) && (!self_pos);   // excluded self -> max key
      kv[kk * 4 + q] = excl ? 0xFFFFFFFFu : f2k(vv[q]);
    }
  }
  const float basef = (float)(wsum_d(bs) * (1.0 / NN));

  // exact rank-KSEL key via bitwise binary search (handles ties exactly):
  // lo = max{u : count(keys < u) <= KSEL}  ==  KSEL-th smallest key
  unsigned lo = 0;
  for (int b = 31; b >= 0; --b) {
    unsigned mid = lo | (1u << b);
    int c = 0;
    #pragma unroll
    for (int t = 0; t < 64; ++t) c += (kv[t] < mid) ? 1 : 0;
    c = wsum_i(c);
    if (c <= KSEL) lo = mid;
  }
  const float thr = k2f(lo);

  // pass 2: weighted sums below threshold, min positive sim, has-pos flag
  double psum = 0.0, nsum = 0.0;
  float minp = __builtin_inff();
  int hasp = 0;
  #pragma unroll
  for (int kk = 0; kk < 16; ++kk) {
    float4 v  = *reinterpret_cast<const float4*>(&sim[w][(kk << 8) + lb]);
    int4  t4  = *reinterpret_cast<const int4*>(tgt + (kk << 8) + lb);
    float vv[4] = {v.x, v.y, v.z, v.w};
    int  tj[4]  = {t4.x, t4.y, t4.z, t4.w};
    #pragma unroll
    for (int q = 0; q < 4; ++q) {
      int j = (kk << 8) + lb + q;
      float s = vv[q];
      bool same = (tj[q] == ti);
      bool vpos = same && ((j == i) ? self_pos : (s < 1.0f));
      if (vpos) minp = fminf(minp, s);
      if (s < thr) {
        float wgt = expf(ALPHA_C * (basef - s));
        if (vpos) { psum += (double)wgt; hasp = 1; }
        else if (!same) nsum += (double)wgt;
      }
    }
  }
  double tpsum = wsum_d(psum);
  double tnsum = wsum_d(nsum);
  float  tminp = wmin_f(minp);
  int    thasp = wsum_i(hasp);

  // diagnostics from the last row only (wave-uniform branch)
  if (i == NN - 1) {
    double pss = 0.0, nss = 0.0;
    int pct = 0, nct = 0;
    for (int kk = 0; kk < 16; ++kk) {
      float4 v  = *reinterpret_cast<const float4*>(&sim[w][(kk << 8) + lb]);
      int4  t4  = *reinterpret_cast<const int4*>(tgt + (kk << 8) + lb);
      float vv[4] = {v.x, v.y, v.z, v.w};
      int  tj[4]  = {t4.x, t4.y, t4.z, t4.w};
      for (int q = 0; q < 4; ++q) {
        int j = (kk << 8) + lb + q;
        float s = vv[q];
        bool same = (tj[q] == ti);
        bool vpos = same && ((j == i) ? self_pos : (s < 1.0f));
        if (vpos) { pss += (double)s; pct++; }
        if (!same) { nss += (double)s; nct++; }
      }
    }
    pss = wsum_d(pss); nss = wsum_d(nss);
    pct = wsum_i(pct); nct = wsum_i(nct);
    if (lane == 0) {
      out[2] = (float)(pss / (double)pct);
      out[3] = (float)(nss / (double)nct);
    }
  }

  if (lane == 0) {
    float pl = (thasp > 0) ? (float)tpsum
                           : expf(ALPHA_C * (basef - tminp));
    row_loss[i] = -logf(pl / (pl + (float)tnsum));
  }
}

// ---- kernel 3: deterministic mean of per-row losses ----
__global__ void nca_final(const float* __restrict__ row_loss, float* __restrict__ out) {
  __shared__ double redd[4];
  int tid = threadIdx.x;
  double s = 0.0;
  for (int i = tid; i < NN; i += 256) s += (double)row_loss[i];
  #pragma unroll
  for (int m = 32; m; m >>= 1) s += __shfl_xor(s, m, 64);
  if ((tid & 63) == 0) redd[tid >> 6] = s;
  __syncthreads();
  if (tid == 0) {
    double tot = redd[0] + redd[1] + redd[2] + redd[3];
    out[0] = (float)(tot * (1.0 / NN));
    out[1] = 0.0f;  // prec stays 0 in torch code
  }
}

extern "C" void kernel_launch(void* const* d_in, const int* in_sizes, int n_in,
                              void* d_out, int out_size, void* d_ws, size_t ws_size,
                              hipStream_t stream) {
  const float* x  = (const float*)d_in[0];
  const int* tgt  = (const int*)d_in[1];
  float* out      = (float*)d_out;
  float* xT       = (float*)d_ws;                 // 2 MB
  float* row_loss = xT + (size_t)NN * DD;         // 16 KB

  nca_transpose<<<512, 256, 0, stream>>>(x, xT);
  nca_rows<<<NN / RB, 256, 0, stream>>>(x, xT, tgt, row_loss, out);
  nca_final<<<1, 256, 0, stream>>>(row_loss, out);
}

// Round 3
// 130.986 us; speedup vs baseline: 3.6039x; 1.4030x over previous
//
#include <hip/hip_runtime.h>
#include <math.h>

#define NN 4096
#define DD 128
#define RB 8            // rows per block == waves per block
#define NT 512          // threads per block
#define ALPHA_C 16.0f
#define KSEL 32         // threshold = (K+1)-th smallest, 0-based index K

// ---- float <-> order-preserving u32 key ----
__device__ __forceinline__ unsigned f2k(float f) {
  unsigned b = __float_as_uint(f);
  return (b & 0x80000000u) ? ~b : (b | 0x80000000u);
}
__device__ __forceinline__ float k2f(unsigned k) {
  unsigned b = (k & 0x80000000u) ? (k & 0x7FFFFFFFu) : ~k;
  return __uint_as_float(b);
}

// ---- wave (64-lane) butterfly reductions ----
__device__ __forceinline__ double wsum_d(double v) {
  #pragma unroll
  for (int m = 32; m; m >>= 1) v += __shfl_xor(v, m, 64);
  return v;
}
__device__ __forceinline__ int wsum_i(int v) {
  #pragma unroll
  for (int m = 32; m; m >>= 1) v += __shfl_xor(v, m, 64);
  return v;
}
__device__ __forceinline__ float wmin_f(float v) {
  #pragma unroll
  for (int m = 32; m; m >>= 1) v = fminf(v, __shfl_xor(v, m, 64));
  return v;
}

// ---- kernel 1: transpose x[N][D] -> xT[D][N] ----
__global__ void nca_transpose(const float* __restrict__ x, float* __restrict__ xT) {
  int idx = blockIdx.x * blockDim.x + threadIdx.x;
  int stride = gridDim.x * blockDim.x;
  for (int i = idx; i < NN * DD; i += stride) {
    int n = i >> 7;        // / DD
    int d = i & (DD - 1);  // % DD
    xT[d * NN + n] = x[i];
  }
}

// ---- kernel 2: 8 rows per block (512 thr); block-wide FMA, then 1 wave = 1 row ----
__global__ __launch_bounds__(NT) void nca_rows(
    const float* __restrict__ x, const float* __restrict__ xT,
    const int* __restrict__ tgt, float* __restrict__ row_loss,
    float* __restrict__ out) {
  __shared__ float xi[RB][DD];      // 4 KB
  __shared__ float sim[RB][NN];     // 128 KB
  __shared__ int   hist[RB][256];   // 8 KB

  const int tid = threadIdx.x;
  const int i0  = blockIdx.x * RB;

  for (int k = tid; k < RB * DD; k += NT)
    xi[k >> 7][k & (DD - 1)] = x[i0 * DD + k];
  __syncthreads();

  // ---- phase 1: thread owns j = k*2048 + tid*4 + q  (k,q -> 8 cols) ----
  float acc[RB][8];
  #pragma unroll
  for (int r = 0; r < RB; ++r)
    #pragma unroll
    for (int c = 0; c < 8; ++c) acc[r][c] = 0.0f;

  const int jb = tid << 2;
  #pragma unroll 2
  for (int d = 0; d < DD; ++d) {
    float a[RB];
    #pragma unroll
    for (int r = 0; r < RB; ++r) a[r] = xi[r][d];
    #pragma unroll
    for (int k = 0; k < 2; ++k) {
      float4 v = *reinterpret_cast<const float4*>(xT + d * NN + (k << 11) + jb);
      float vv[4] = {v.x, v.y, v.z, v.w};
      #pragma unroll
      for (int q = 0; q < 4; ++q)
        #pragma unroll
        for (int r = 0; r < RB; ++r)
          acc[r][k * 4 + q] = fmaf(a[r], vv[q], acc[r][k * 4 + q]);
    }
  }

  // ---- redistribute sims to LDS ----
  #pragma unroll
  for (int r = 0; r < RB; ++r)
    #pragma unroll
    for (int k = 0; k < 2; ++k) {
      float4 v = make_float4(acc[r][k * 4 + 0], acc[r][k * 4 + 1],
                             acc[r][k * 4 + 2], acc[r][k * 4 + 3]);
      *reinterpret_cast<float4*>(&sim[r][(k << 11) + jb]) = v;
    }
  __syncthreads();

  // ---- phase 2: wave w owns row i0+w; lane owns j = kk*256 + lane*4 + q ----
  const int w    = tid >> 6;
  const int lane = tid & 63;
  const int i    = i0 + w;
  const int ti   = tgt[i];
  const int lb   = lane << 2;

  // f64 self-dot (decision sim[i][i] < 1.0 must match f64-accurate reference)
  double sx0 = (double)xi[w][lane], sx1 = (double)xi[w][lane + 64];
  const double selfd = wsum_d(sx0 * sx0 + sx1 * sx1);
  const bool self_pos = (selfd < 1.0);

  // build keys + base (row mean, f64 sum); excluded self -> max key (NaN on decode)
  unsigned kv[64];
  double bs = 0.0;
  #pragma unroll
  for (int kk = 0; kk < 16; ++kk) {
    float4 v = *reinterpret_cast<const float4*>(&sim[w][(kk << 8) + lb]);
    float vv[4] = {v.x, v.y, v.z, v.w};
    #pragma unroll
    for (int q = 0; q < 4; ++q) {
      int j = (kk << 8) + lb + q;
      bs += (double)vv[q];
      bool excl = (j == i) && (!self_pos);
      kv[kk * 4 + q] = excl ? 0xFFFFFFFFu : f2k(vv[q]);
    }
  }
  const float basef = (float)(wsum_d(bs) * (1.0 / NN));

  // ---- exact rank-KSEL via 4-round radix-256 histogram select ----
  unsigned pref = 0;
  int want = KSEL;
  #pragma unroll
  for (int r = 0; r < 4; ++r) {
    *reinterpret_cast<int4*>(&hist[w][lane << 2]) = make_int4(0, 0, 0, 0);
    // same-wave DS ordering: zeros land before atomics below
    #pragma unroll
    for (int t = 0; t < 64; ++t) {
      bool m = (r == 0) || ((kv[t] >> (32 - 8 * r)) == pref);
      if (m) atomicAdd(&hist[w][(kv[t] >> (24 - 8 * r)) & 0xFFu], 1);
    }
    int4 c4 = *reinterpret_cast<const int4*>(&hist[w][lane << 2]);
    int tot = c4.x + c4.y + c4.z + c4.w;
    int incl = tot;
    #pragma unroll
    for (int off = 1; off < 64; off <<= 1) {
      int o = __shfl_up(incl, off, 64);
      if (lane >= off) incl += o;
    }
    int excl = incl - tot;
    bool here = (want >= excl) && (want < incl);
    unsigned long long bal = __ballot(here);
    int L = __ffsll((unsigned long long)bal) - 1;
    int binl = 0, wl = want - excl;          // meaningful on lane L only
    if (wl >= c4.x) { wl -= c4.x; binl = 1;
      if (wl >= c4.y) { wl -= c4.y; binl = 2;
        if (wl >= c4.z) { wl -= c4.z; binl = 3; } } }
    int binsel = __shfl((lane << 2) + binl, L, 64);
    want = __shfl(wl, L, 64);
    pref = (pref << 8) | (unsigned)binsel;
  }
  const float thr = k2f(pref);

  // ---- pass 2: weighted sums below threshold, min positive, has-pos ----
  double psum = 0.0, nsum = 0.0;
  float minp = __builtin_inff();
  int hasp = 0;
  #pragma unroll
  for (int kk = 0; kk < 16; ++kk) {
    int4 t4 = *reinterpret_cast<const int4*>(tgt + (kk << 8) + lb);
    int tj[4] = {t4.x, t4.y, t4.z, t4.w};
    #pragma unroll
    for (int q = 0; q < 4; ++q) {
      int t = kk * 4 + q;
      int j = (kk << 8) + lb + q;
      float s = k2f(kv[t]);   // NaN for excluded self -> all predicates false
      bool same = (tj[q] == ti);
      bool vpos = same && ((j == i) ? self_pos : (s < 1.0f));
      if (vpos) minp = fminf(minp, s);
      if (s < thr) {
        float wgt = expf(ALPHA_C * (basef - s));
        if (vpos) { psum += (double)wgt; hasp = 1; }
        else if (!same) nsum += (double)wgt;
      }
    }
  }
  double tpsum = wsum_d(psum);
  double tnsum = wsum_d(nsum);
  float  tminp = wmin_f(minp);
  int    thasp = wsum_i(hasp);

  // diagnostics from the last row only (wave-uniform branch)
  if (i == NN - 1) {
    double pss = 0.0, nss = 0.0;
    int pct = 0, nct = 0;
    #pragma unroll
    for (int kk = 0; kk < 16; ++kk) {
      int4 t4 = *reinterpret_cast<const int4*>(tgt + (kk << 8) + lb);
      int tj[4] = {t4.x, t4.y, t4.z, t4.w};
      #pragma unroll
      for (int q = 0; q < 4; ++q) {
        int t = kk * 4 + q;
        int j = (kk << 8) + lb + q;
        float s = k2f(kv[t]);
        bool same = (tj[q] == ti);
        bool vpos = same && ((j == i) ? self_pos : (s < 1.0f));
        if (vpos) { pss += (double)s; pct++; }
        if (!same) { nss += (double)s; nct++; }
      }
    }
    pss = wsum_d(pss); nss = wsum_d(nss);
    pct = wsum_i(pct); nct = wsum_i(nct);
    if (lane == 0) {
      out[2] = (float)(pss / (double)pct);
      out[3] = (float)(nss / (double)nct);
    }
  }

  if (lane == 0) {
    float pl = (thasp > 0) ? (float)tpsum
                           : expf(ALPHA_C * (basef - tminp));
    row_loss[i] = -logf(pl / (pl + (float)tnsum));
  }
}

// ---- kernel 3: deterministic mean of per-row losses ----
__global__ void nca_final(const float* __restrict__ row_loss, float* __restrict__ out) {
  __shared__ double redd[4];
  int tid = threadIdx.x;
  double s = 0.0;
  for (int i = tid; i < NN; i += 256) s += (double)row_loss[i];
  #pragma unroll
  for (int m = 32; m; m >>= 1) s += __shfl_xor(s, m, 64);
  if ((tid & 63) == 0) redd[tid >> 6] = s;
  __syncthreads();
  if (tid == 0) {
    double tot = redd[0] + redd[1] + redd[2] + redd[3];
    out[0] = (float)(tot * (1.0 / NN));
    out[1] = 0.0f;  // prec stays 0 in torch code
  }
}

extern "C" void kernel_launch(void* const* d_in, const int* in_sizes, int n_in,
                              void* d_out, int out_size, void* d_ws, size_t ws_size,
                              hipStream_t stream) {
  const float* x  = (const float*)d_in[0];
  const int* tgt  = (const int*)d_in[1];
  float* out      = (float*)d_out;
  float* xT       = (float*)d_ws;                 // 2 MB
  float* row_loss = xT + (size_t)NN * DD;         // 16 KB

  nca_transpose<<<512, 256, 0, stream>>>(x, xT);
  nca_rows<<<NN / RB, NT, 0, stream>>>(x, xT, tgt, row_loss, out);
  nca_final<<<1, 256, 0, stream>>>(row_loss, out);
}